// Round 6
// baseline (31.647 us; speedup 1.0000x reference)
//
#include <hip/hip_runtime.h>
#include <math.h>

// Problem constants
#define B_SZ   8192
#define D_IN   512
#define M0_N   128
#define M1_N   128
#define K_TOP  8
#define H_DIM  128
#define ROWS   16          // batch rows per compute block

// ws layout (ints):
//   [0..1]       idx_out  (top-2 modules of emb_out)
//   [64..1087]   pre1[col*8+r] : top-8 of emb1[task][:,col], all 128 cols
//   [2048..3071] pre0[col*8+r] : top-8 of emb0[task][:,col], all 128 cols

// ---------------------------------------------------------------------------
// Wave-parallel iterative top-k, jax.lax.top_k semantics (descending value,
// ties -> lowest index). NCH*64 candidates; lane 0 writes out_idx.
template<int NCH>
__device__ __forceinline__ void wave_topk(const float* __restrict__ base,
                                          int stride, int k, int* out_idx,
                                          int lane) {
  float v[NCH];
#pragma unroll
  for (int t = 0; t < NCH; ++t) v[t] = base[(t * 64 + lane) * stride];
  for (int r = 0; r < k; ++r) {
    float bv = -INFINITY;
    int bd = 0x7fffffff;
#pragma unroll
    for (int t = 0; t < NCH; ++t) {
      if (v[t] > bv) { bv = v[t]; bd = t * 64 + lane; }
    }
#pragma unroll
    for (int m = 1; m < 64; m <<= 1) {
      float ov = __shfl_xor(bv, m, 64);
      int   od = __shfl_xor(bd, m, 64);
      if (ov > bv || (ov == bv && od < bd)) { bv = ov; bd = od; }
    }
    if (lane == 0) out_idx[r] = bd;
    if ((bd & 63) == lane) {
      const int tw = bd >> 6;
#pragma unroll
      for (int tt = 0; tt < NCH; ++tt)
        if (tt == tw) v[tt] = -INFINITY;
    }
  }
}

// ---------------------------------------------------------------------------
// Speculative routing spread over 257 one-wave blocks (all CUs engaged):
// blocks 0..127: emb1 col top-8; 128..255: emb0 col top-8; 256: emb_out top-2.
__global__ __launch_bounds__(64)
void route_pre(const int* __restrict__ task_id_p,
               const float* __restrict__ emb0,
               const float* __restrict__ emb1,
               const float* __restrict__ emb_out,
               int* __restrict__ ws) {
  const int task = task_id_p[0];
  const int lane = threadIdx.x;
  const int b    = blockIdx.x;
  if (b < 128) {
    wave_topk<2>(emb1 + (size_t)task * M0_N * M1_N + b, M1_N, K_TOP,
                 ws + 64 + b * 8, lane);
  } else if (b < 256) {
    const int col = b - 128;
    wave_topk<8>(emb0 + (size_t)task * D_IN * M0_N + col, M0_N, K_TOP,
                 ws + 2048 + col * 8, lane);
  } else {
    wave_topk<2>(emb_out + task * M1_N, 1, 2, ws, lane);
  }
}

// ---------------------------------------------------------------------------
// Per-slot parameter load into a named register set (software pipeline stage).
__device__ __forceinline__ void load_slot(const float* __restrict__ W1,
                                          const float* __restrict__ b1,
                                          const float* __restrict__ W2,
                                          const float* __restrict__ b2,
                                          int m0, const int* __restrict__ cols,
                                          const float* __restrict__ xr0,
                                          const float* __restrict__ xr1, int g,
                                          float4 (&w1v)[8], float4& b1v,
                                          float4& w2v, float& b2v,
                                          float (&xv0)[8], float (&xv1)[8]) {
  const float4* w1p = (const float4*)(W1 + (size_t)m0 * (K_TOP * H_DIM));
#pragma unroll
  for (int k = 0; k < 8; ++k) w1v[k] = w1p[k * 32 + g];
  b1v = ((const float4*)(b1 + m0 * H_DIM))[g];
  w2v = ((const float4*)(W2 + m0 * H_DIM))[g];
  b2v = b2[m0];
#pragma unroll
  for (int k = 0; k < 8; ++k) {
    const int c = cols[k];
    xv0[k] = xr0[c];
    xv1[k] = xr1[c];
  }
}

// MLP for 2 rows + 32-lane reduce; returns per-row sums on all lanes.
__device__ __forceinline__ void compute_slot(const float4 (&w1v)[8],
                                             const float4& b1v,
                                             const float4& w2v,
                                             const float (&xv0)[8],
                                             const float (&xv1)[8],
                                             float& p0o, float& p1o) {
  float4 h0 = b1v, h1 = b1v;
#pragma unroll
  for (int k = 0; k < 8; ++k) {
    h0.x = fmaf(xv0[k], w1v[k].x, h0.x);
    h0.y = fmaf(xv0[k], w1v[k].y, h0.y);
    h0.z = fmaf(xv0[k], w1v[k].z, h0.z);
    h0.w = fmaf(xv0[k], w1v[k].w, h0.w);
    h1.x = fmaf(xv1[k], w1v[k].x, h1.x);
    h1.y = fmaf(xv1[k], w1v[k].y, h1.y);
    h1.z = fmaf(xv1[k], w1v[k].z, h1.z);
    h1.w = fmaf(xv1[k], w1v[k].w, h1.w);
  }
  float p0 = 0.f, p1 = 0.f;
  p0 = fmaf(fmaxf(h0.x, 0.f), w2v.x, p0);
  p0 = fmaf(fmaxf(h0.y, 0.f), w2v.y, p0);
  p0 = fmaf(fmaxf(h0.z, 0.f), w2v.z, p0);
  p0 = fmaf(fmaxf(h0.w, 0.f), w2v.w, p0);
  p1 = fmaf(fmaxf(h1.x, 0.f), w2v.x, p1);
  p1 = fmaf(fmaxf(h1.y, 0.f), w2v.y, p1);
  p1 = fmaf(fmaxf(h1.z, 0.f), w2v.z, p1);
  p1 = fmaf(fmaxf(h1.w, 0.f), w2v.w, p1);
#pragma unroll
  for (int m = 1; m < 32; m <<= 1) {
    p0 += __shfl_xor(p0, m, 64);
    p1 += __shfl_xor(p1, m, 64);
  }
  p0o = p0;
  p1o = p1;
}

// ---------------------------------------------------------------------------
// Fused compute: layer0 (16 positional slots, 1-slot-lookahead software
// pipeline) + layer1 (2 modules) + sigmoid. Thread (g=tid&31, rl=tid>>5)
// owns hidden units 4g..4g+3 of rows {2rl, 2rl+1}.
__global__ __launch_bounds__(256, 2)
void fused_compute(const float* __restrict__ x,
                   const float* __restrict__ W1_0, const float* __restrict__ b1_0,
                   const float* __restrict__ W2_0, const float* __restrict__ b2_0,
                   const float* __restrict__ W1_1, const float* __restrict__ b1_1,
                   const float* __restrict__ W2_1, const float* __restrict__ b2_1,
                   const int* __restrict__ ws, float* __restrict__ out) {
  __shared__ int   s_m1[2];
  __shared__ int   s_m0[16];
  __shared__ int   s_cols[128];
  __shared__ float tile[16 * 18];       // layer-0 outputs [slot][row]

  const int tid = threadIdx.x;
  const int rowbase = blockIdx.x * ROWS;

  // resolve routing indirection: per-thread dependent chain, ONE barrier
  if (tid < 128) {
    const int slot = tid >> 3, k = tid & 7;
    const int m1 = ws[slot >> 3];
    const int m0 = ws[64 + m1 * 8 + (slot & 7)];
    if (k == 0) s_m0[slot] = m0;
    s_cols[tid] = ws[2048 + m0 * 8 + k];
    if (tid < 2) s_m1[tid] = ws[tid];
  }
  __syncthreads();

  const int g  = tid & 31;              // h-group: units 4g..4g+3
  const int rl = tid >> 5;              // row pair 0..7
  const int r0 = rl * 2, r1 = r0 + 1;
  const float* xr0 = x + (size_t)(rowbase + r0) * D_IN;
  const float* xr1 = x + (size_t)(rowbase + r1) * D_IN;

  // ---- layer 0: 16 slots, double-buffered register pipeline ----
  float4 wA[8], bA, vA; float b2A; float x0A[8], x1A[8];
  float4 wB[8], bB, vB; float b2B; float x0B[8], x1B[8];

  load_slot(W1_0, b1_0, W2_0, b2_0, s_m0[0], s_cols, xr0, xr1, g,
            wA, bA, vA, b2A, x0A, x1A);
#pragma unroll
  for (int sp = 0; sp < 8; ++sp) {
    const int s0 = 2 * sp, s1 = s0 + 1;
    load_slot(W1_0, b1_0, W2_0, b2_0, s_m0[s1], s_cols + s1 * 8, xr0, xr1, g,
              wB, bB, vB, b2B, x0B, x1B);
    {
      float p0, p1;
      compute_slot(wA, bA, vA, x0A, x1A, p0, p1);
      if (g == 0) {
        tile[s0 * 18 + r0] = p0 + b2A;
        tile[s0 * 18 + r1] = p1 + b2A;
      }
    }
    if (sp < 7)
      load_slot(W1_0, b1_0, W2_0, b2_0, s_m0[s0 + 2], s_cols + (s0 + 2) * 8,
                xr0, xr1, g, wA, bA, vA, b2A, x0A, x1A);
    {
      float p0, p1;
      compute_slot(wB, bB, vB, x0B, x1B, p0, p1);
      if (g == 0) {
        tile[s1 * 18 + r0] = p0 + b2B;
        tile[s1 * 18 + r1] = p1 + b2B;
      }
    }
  }
  __syncthreads();

  // ---- layer 1 (2 modules) + sigmoid ----
#pragma unroll
  for (int j = 0; j < 2; ++j) {
    const int m1 = s_m1[j];
    const float4* w1p = (const float4*)(W1_1 + (size_t)m1 * (K_TOP * H_DIM));
    float4 w1v[8];
#pragma unroll
    for (int k = 0; k < 8; ++k) w1v[k] = w1p[k * 32 + g];
    const float4 b1v = ((const float4*)(b1_1 + m1 * H_DIM))[g];
    const float4 w2v = ((const float4*)(W2_1 + m1 * H_DIM))[g];
    const float  b2v = b2_1[m1];

    float xv0[8], xv1[8];
#pragma unroll
    for (int k = 0; k < 8; ++k) {
      xv0[k] = tile[(j * 8 + k) * 18 + r0];
      xv1[k] = tile[(j * 8 + k) * 18 + r1];
    }
    float p0, p1;
    {
      float4 h0 = b1v, h1 = b1v;
#pragma unroll
      for (int k = 0; k < 8; ++k) {
        h0.x = fmaf(xv0[k], w1v[k].x, h0.x);
        h0.y = fmaf(xv0[k], w1v[k].y, h0.y);
        h0.z = fmaf(xv0[k], w1v[k].z, h0.z);
        h0.w = fmaf(xv0[k], w1v[k].w, h0.w);
        h1.x = fmaf(xv1[k], w1v[k].x, h1.x);
        h1.y = fmaf(xv1[k], w1v[k].y, h1.y);
        h1.z = fmaf(xv1[k], w1v[k].z, h1.z);
        h1.w = fmaf(xv1[k], w1v[k].w, h1.w);
      }
      p0 = 0.f; p1 = 0.f;
      p0 = fmaf(fmaxf(h0.x, 0.f), w2v.x, p0);
      p0 = fmaf(fmaxf(h0.y, 0.f), w2v.y, p0);
      p0 = fmaf(fmaxf(h0.z, 0.f), w2v.z, p0);
      p0 = fmaf(fmaxf(h0.w, 0.f), w2v.w, p0);
      p1 = fmaf(fmaxf(h1.x, 0.f), w2v.x, p1);
      p1 = fmaf(fmaxf(h1.y, 0.f), w2v.y, p1);
      p1 = fmaf(fmaxf(h1.z, 0.f), w2v.z, p1);
      p1 = fmaf(fmaxf(h1.w, 0.f), w2v.w, p1);
#pragma unroll
      for (int m = 1; m < 32; m <<= 1) {
        p0 += __shfl_xor(p0, m, 64);
        p1 += __shfl_xor(p1, m, 64);
      }
    }
    if (g == 0) {
      const float v0 = p0 + b2v;
      const float v1 = p1 + b2v;
      out[(size_t)(rowbase + r0) * 2 + j] = 1.f / (1.f + __expf(-v0));
      out[(size_t)(rowbase + r1) * 2 + j] = 1.f / (1.f + __expf(-v1));
    }
  }
}

// ---------------------------------------------------------------------------
extern "C" void kernel_launch(void* const* d_in, const int* in_sizes, int n_in,
                              void* d_out, int out_size, void* d_ws, size_t ws_size,
                              hipStream_t stream) {
  const float* x       = (const float*)d_in[0];
  const int*   task_id = (const int*)  d_in[1];
  const float* emb0    = (const float*)d_in[2];
  const float* emb1    = (const float*)d_in[3];
  const float* emb_out = (const float*)d_in[4];
  const float* W1_0    = (const float*)d_in[5];
  const float* b1_0    = (const float*)d_in[6];
  const float* W2_0    = (const float*)d_in[7];
  const float* b2_0    = (const float*)d_in[8];
  const float* W1_1    = (const float*)d_in[9];
  const float* b1_1    = (const float*)d_in[10];
  const float* W2_1    = (const float*)d_in[11];
  const float* b2_1    = (const float*)d_in[12];

  int* ws = (int*)d_ws;

  route_pre<<<257, 64, 0, stream>>>(task_id, emb0, emb1, emb_out, ws);
  fused_compute<<<B_SZ / ROWS, 256, 0, stream>>>(x, W1_0, b1_0, W2_0, b2_0,
                                                 W1_1, b1_1, W2_1, b2_1,
                                                 ws, (float*)d_out);
}